// Round 2
// baseline (546.833 us; speedup 1.0000x reference)
//
#include <hip/hip_runtime.h>
#include <math.h>

#define B_SZ   256
#define D_IN   2048
#define HID    2048
#define NSEG   10
#define D_CTX  1024
#define OUT_N  100
#define KWIN   102
#define CAP    256   // FF compaction cap (mean 102, +15 sigma safe)
#define CAPS   128   // per-seg compaction cap (mean 51.2, +11 sigma safe)

typedef float f32x4 __attribute__((ext_vector_type(4)));

// non-temporal 16B load: mask/weight streams must not evict L2-resident activations
__device__ __forceinline__ f32x4 ntld4(const float* p) {
  return __builtin_nontemporal_load((const f32x4*)p);
}

// ---------- sortable-key helpers for exact fp32 top-k ----------
__device__ __forceinline__ unsigned f2key(float f) {
  unsigned b = __float_as_uint(f);
  return (b & 0x80000000u) ? ~b : (b | 0x80000000u);
}
__device__ __forceinline__ float key2f(unsigned k) {
  return (k & 0x80000000u) ? __uint_as_float(k & 0x7FFFFFFFu) : __uint_as_float(~k);
}

// ---------- combined transpose for x and ctx (one launch) ----------
__global__ __launch_bounds__(256) void transpose2_k(const float* __restrict__ xsrc,
                                                    float* __restrict__ xdst,
                                                    const float* __restrict__ csrc,
                                                    float* __restrict__ cdst) {
  __shared__ float tile[32][33];
  int bid = blockIdx.x;
  const float* src; float* dst; int cols;
  const int NX = (D_IN / 32) * (B_SZ / 32);  // 512
  if (bid < NX) { src = xsrc; dst = xdst; cols = D_IN; }
  else { bid -= NX; src = csrc; dst = cdst; cols = D_CTX; }
  int nbx = cols / 32;
  int bx = bid % nbx, by = bid / nbx;
  int c0 = bx * 32, r0 = by * 32;
  int tx = threadIdx.x & 31, ty = threadIdx.x >> 5;
  for (int i = ty; i < 32; i += 8)
    tile[i][tx] = src[(r0 + i) * cols + (c0 + tx)];
  __syncthreads();
  for (int i = ty; i < 32; i += 8)
    dst[(c0 + i) * B_SZ + (r0 + tx)] = tile[tx][i];
}

// ---------- sparse dot with pair buffer (w,c): used by ff_kernel ----------
__device__ __forceinline__ void gather_dot(const float* __restrict__ src,
                                           const float2* pairs, int cnt,
                                           int t4, float out4[4]) {
  float acc[4][4];
#pragma unroll
  for (int s = 0; s < 4; ++s)
#pragma unroll
    for (int i = 0; i < 4; ++i) acc[s][i] = 0.f;
  int j = 0;
  for (; j + 8 <= cnt; j += 8) {
#pragma unroll
    for (int s = 0; s < 8; ++s) {
      float2 p = pairs[j + s];
      const f32x4 cv = *(const f32x4*)(src + (__float_as_int(p.y) << 8) + t4);
      acc[s & 3][0] += cv.x * p.x; acc[s & 3][1] += cv.y * p.x;
      acc[s & 3][2] += cv.z * p.x; acc[s & 3][3] += cv.w * p.x;
    }
  }
  for (; j < cnt; ++j) {
    float2 p = pairs[j];
    const f32x4 cv = *(const f32x4*)(src + (__float_as_int(p.y) << 8) + t4);
    acc[0][0] += cv.x * p.x; acc[0][1] += cv.y * p.x;
    acc[0][2] += cv.z * p.x; acc[0][3] += cv.w * p.x;
  }
#pragma unroll
  for (int i = 0; i < 4; ++i)
    out4[i] = (acc[0][i] + acc[1][i]) + (acc[2][i] + acc[3][i]);
}

// ---------- lean dend helpers: mask-only prefetch, index compaction ----------
__device__ __forceinline__ void load_mask(const float* __restrict__ mrow, f32x4 m[4]) {
  const int t = threadIdx.x & 63;
#pragma unroll
  for (int i = 0; i < 4; ++i) m[i] = ntld4(mrow + 4 * (t + 64 * i));
}

// ballot-compact indices of nonzero mask elements (from prefetched regs) into LDS
__device__ __forceinline__ int compact_idx_ballot(const f32x4 m[4], int* idx) {
  const int t = threadIdx.x & 63;
  const unsigned long long below = (1ull << t) - 1ull;
  __builtin_amdgcn_wave_barrier();   // don't migrate writes above prior reads
  int base = 0;
#pragma unroll
  for (int i = 0; i < 4; ++i) {
    const int c = (t + 64 * i) << 2;
    const float mv[4] = {m[i].x, m[i].y, m[i].z, m[i].w};
#pragma unroll
    for (int j = 0; j < 4; ++j) {
      bool nz = (mv[j] != 0.f);
      unsigned long long bal = __ballot(nz);
      if (nz) {
        int pos = base + (int)__popcll(bal & below);
        if (pos < CAPS) idx[pos] = c + j;
      }
      base += (int)__popcll(bal);
    }
  }
  __builtin_amdgcn_wave_barrier();
  return base > CAPS ? CAPS : base;
}

// sparse dot: index list in LDS, weight fetched at use (wave-uniform broadcast load)
__device__ __forceinline__ void gather_dot_w(const float* __restrict__ src,
                                             const float* __restrict__ wrow,
                                             const int* idx, int cnt,
                                             int t4, float out4[4]) {
  float acc[4][4];
#pragma unroll
  for (int s = 0; s < 4; ++s)
#pragma unroll
    for (int i = 0; i < 4; ++i) acc[s][i] = 0.f;
  int j = 0;
  for (; j + 8 <= cnt; j += 8) {
#pragma unroll
    for (int s = 0; s < 8; ++s) {
      int c = idx[j + s];
      float wv = wrow[c];
      const f32x4 cv = *(const f32x4*)(src + (c << 8) + t4);
      acc[s & 3][0] += cv.x * wv; acc[s & 3][1] += cv.y * wv;
      acc[s & 3][2] += cv.z * wv; acc[s & 3][3] += cv.w * wv;
    }
  }
  for (; j < cnt; ++j) {
    int c = idx[j];
    float wv = wrow[c];
    const f32x4 cv = *(const f32x4*)(src + (c << 8) + t4);
    acc[0][0] += cv.x * wv; acc[0][1] += cv.y * wv;
    acc[0][2] += cv.z * wv; acc[0][3] += cv.w * wv;
  }
#pragma unroll
  for (int i = 0; i < 4; ++i)
    out4[i] = (acc[0][i] + acc[1][i]) + (acc[2][i] + acc[3][i]);
}

// ---------- dendrite gates: 8192 uniform waves, 2 waves per unit (segs 0-4 / 5-9) ----------
// Lean form: stream ONLY the mask (16 prefetch regs); weights broadcast-gathered at use.
// ~50 live VGPRs -> no spill at (256,3); segW HBM stream drops to touched lines (~56%).
__global__ __launch_bounds__(256, 3) void dend_gates_kernel(
    const float* __restrict__ segW1, const float* __restrict__ maskS1,
    const float* __restrict__ segW2, const float* __restrict__ maskS2,
    const float* __restrict__ ctxT,
    float* __restrict__ gate1T, float* __restrict__ gate2T) {
  __shared__ int idx_s[4][CAPS];
  __shared__ float exch[2][64][9];   // +1 pad: avoid bank conflicts
  const int wave = threadIdx.x >> 6;
  const int t = threadIdx.x & 63, t4 = t * 4;
  const int pidx = wave >> 1;        // unit-in-block (0 or 1)
  const int half = wave & 1;         // 0 -> segs 0..4, 1 -> segs 5..9
  const int row = blockIdx.x * 2 + pidx;       // 0..4095
  const bool isL1 = (row < HID);
  const int u = isL1 ? row : (row - HID);
  const float* segW = (isL1 ? segW1 : segW2)
                      + (size_t)u * NSEG * D_CTX + (size_t)half * 5 * D_CTX;
  const float* maskS = (isL1 ? maskS1 : maskS2)
                      + (size_t)u * NSEG * D_CTX + (size_t)half * 5 * D_CTX;
  int* idx = idx_s[wave];

  float bestA[4] = {-1.f, -1.f, -1.f, -1.f};
  float chosen[4] = {0.f, 0.f, 0.f, 0.f};

  f32x4 m[4];
  load_mask(maskS, m);
#pragma unroll 1
  for (int s = 0; s < 5; ++s) {
    int cnt = compact_idx_ballot(m, idx);        // consumes prefetched mask regs
    if (s + 1 < 5)
      load_mask(maskS + (s + 1) * D_CTX, m);     // issue-only prefetch
    float d[4];
    gather_dot_w(ctxT, segW + s * D_CTX, idx, cnt, t4, d);
#pragma unroll
    for (int i = 0; i < 4; ++i) {
      float a = fabsf(d[i]);
      if (a > bestA[i]) { bestA[i] = a; chosen[i] = d[i]; }  // strict > == first occurrence
    }
  }

  if (half) {
#pragma unroll
    for (int i = 0; i < 4; ++i) {
      exch[pidx][t][i] = bestA[i];
      exch[pidx][t][4 + i] = chosen[i];
    }
  }
  __syncthreads();
  if (!half) {
#pragma unroll
    for (int i = 0; i < 4; ++i) {
      float a1 = exch[pidx][t][i];
      if (a1 > bestA[i]) chosen[i] = exch[pidx][t][4 + i];  // half-0 wins ties (lower seg)
    }
    float4 g;
    g.x = 1.f / (1.f + expf(-chosen[0]));
    g.y = 1.f / (1.f + expf(-chosen[1]));
    g.z = 1.f / (1.f + expf(-chosen[2]));
    g.w = 1.f / (1.f + expf(-chosen[3]));
    float* gT = isL1 ? gate1T : gate2T;
    *(float4*)(gT + (size_t)u * B_SZ + t4) = g;
  }
}

// ---------- generic masked-FF + gate kernel (D_IN == HID == 2048): 4 waves/block ----------
__global__ __launch_bounds__(256, 4) void ff_kernel(
    const float* __restrict__ W, const float* __restrict__ maskW, const float* __restrict__ b,
    const float* __restrict__ srcT, const float* __restrict__ gateT, float* __restrict__ yT) {
  __shared__ float2 pairs_s[4][CAP];
  const int wave = threadIdx.x >> 6;
  const int t = threadIdx.x & 63, t4 = t * 4;
  const int u = blockIdx.x * 4 + wave;
  float2* pairs = pairs_s[wave];
  const float* wrow = W + (size_t)u * HID;
  const float* mrow = maskW + (size_t)u * HID;
  const unsigned long long below = (1ull << t) - 1ull;
  int base = 0;
  for (int e = t; e < HID / 4; e += 64) {      // uniform trip count: ballots legal
    f32x4 ww = ntld4(wrow + 4 * e);
    f32x4 mm = ntld4(mrow + 4 * e);
    const float wv[4] = {ww.x, ww.y, ww.z, ww.w};
    const float mv[4] = {mm.x, mm.y, mm.z, mm.w};
    const int c = e << 2;
#pragma unroll
    for (int j = 0; j < 4; ++j) {
      bool nz = (mv[j] != 0.f);
      unsigned long long bal = __ballot(nz);
      if (nz) {
        int pos = base + (int)__popcll(bal & below);
        if (pos < CAP) pairs[pos] = make_float2(wv[j], __int_as_float(c + j));
      }
      base += (int)__popcll(bal);
    }
  }
  __builtin_amdgcn_wave_barrier();
  int cnt = base > CAP ? CAP : base;
  float acc[4];
  gather_dot(srcT, pairs, cnt, t4, acc);
  float bb = b[u];
  float4 g = *(const float4*)(gateT + (size_t)u * B_SZ + t4);
  float4 o;
  o.x = (acc[0] + bb) * g.x; o.y = (acc[1] + bb) * g.y;
  o.z = (acc[2] + bb) * g.z; o.w = (acc[3] + bb) * g.w;
  *(float4*)(yT + (size_t)u * B_SZ + t4) = o;
}

// ---------- exact top-K per batch column: wave-per-column ballot binary search ----------
// One 64-thread block per column b. Lane t owns elements u = t*32+i (index order).
// Greedy MSB->LSB search for T = key of K-th largest; zero barriers, zero atomics.
// mode 0: write in place ([HID][B] layout); mode 1: write rows dst[b][HID]
__global__ __launch_bounds__(64) void topk_kernel(const float* __restrict__ yT,
                                                  float* __restrict__ dst, int mode) {
  const int b = blockIdx.x, t = threadIdx.x;
  unsigned k[32];
#pragma unroll
  for (int i = 0; i < 32; ++i)
    k[i] = f2key(yT[(size_t)(t * 32 + i) * B_SZ + b]);
  // T := max value with count(key >= T) >= KWIN  (== K-th largest key, duplicates counted)
  unsigned T = 0u;
  for (int bit = 31; bit >= 0; --bit) {
    unsigned cand = T | (1u << bit);
    int cnt = 0;
#pragma unroll
    for (int i = 0; i < 32; ++i)
      cnt += (int)__popcll(__ballot(k[i] >= cand));   // uniform across lanes
    if (cnt >= KWIN) T = cand;
  }
  int cntGT = 0;
#pragma unroll
  for (int i = 0; i < 32; ++i)
    cntGT += (int)__popcll(__ballot(k[i] > T));
  const int rem = KWIN - cntGT;   // how many key==T survive (stable, index order)
  // exclusive prefix (over lanes) of per-lane equal counts
  int e = 0;
#pragma unroll
  for (int i = 0; i < 32; ++i) e += (k[i] == T) ? 1 : 0;
  int scan = e;
#pragma unroll
  for (int off = 1; off < 64; off <<= 1) {
    int v = __shfl_up(scan, off, 64);
    if (t >= off) scan += v;
  }
  int tk = scan - e;   // equals in lanes < t
#pragma unroll
  for (int i = 0; i < 32; ++i) {
    bool eq = (k[i] == T);
    bool keep = (k[i] > T) || (eq && tk < rem);
    tk += eq ? 1 : 0;
    float f = keep ? key2f(k[i]) : 0.f;
    int uu = t * 32 + i;
    if (mode == 0) dst[(size_t)uu * B_SZ + b] = f;
    else dst[(size_t)b * HID + uu] = f;
  }
}

// ---------- Dale output head ----------
__global__ __launch_bounds__(256) void out_kernel(
    const float* __restrict__ h2, const float* __restrict__ Wex, const float* __restrict__ Wix,
    const float* __restrict__ Wei, const float* __restrict__ bo, float* __restrict__ out) {
  const int b = blockIdx.x, t = threadIdx.x;
  __shared__ float hrow[HID];
  __shared__ float red[256];
  float part = 0.f;
#pragma unroll
  for (int i = 0; i < 8; ++i) {
    int u = t + 256 * i;
    float v = h2[(size_t)b * HID + u];
    hrow[u] = v;
    part += v * Wix[u];
  }
  red[t] = part;
  __syncthreads();
  for (int off = 128; off > 0; off >>= 1) {
    if (t < off) red[t] += red[t + off];
    __syncthreads();
  }
  float S = red[0];
  const int w = t >> 6, l = t & 63;
  for (int o = w; o < OUT_N; o += 4) {
    float acc = 0.f;
    const float* wr = Wex + (size_t)o * HID;
#pragma unroll
    for (int q = 0; q < HID / 64; ++q) acc += hrow[l + 64 * q] * wr[l + 64 * q];
    for (int off = 32; off > 0; off >>= 1) acc += __shfl_down(acc, off, 64);
    if (l == 0) out[(size_t)b * OUT_N + o] = acc - Wei[o] * S + bo[o];
  }
}

extern "C" void kernel_launch(void* const* d_in, const int* in_sizes, int n_in,
                              void* d_out, int out_size, void* d_ws, size_t ws_size,
                              hipStream_t stream) {
  const float* x      = (const float*)d_in[0];
  const float* ctx    = (const float*)d_in[1];
  const float* W1     = (const float*)d_in[2];
  const float* b1     = (const float*)d_in[3];
  const float* segW1  = (const float*)d_in[4];
  const float* maskW1 = (const float*)d_in[5];
  const float* maskS1 = (const float*)d_in[6];
  const float* W2     = (const float*)d_in[7];
  const float* b2     = (const float*)d_in[8];
  const float* segW2  = (const float*)d_in[9];
  const float* maskW2 = (const float*)d_in[10];
  const float* maskS2 = (const float*)d_in[11];
  const float* Wex    = (const float*)d_in[12];
  const float* Wix    = (const float*)d_in[13];
  const float* Wei    = (const float*)d_in[14];
  const float* bo     = (const float*)d_in[15];
  float* out = (float*)d_out;
  float* ws = (float*)d_ws;

  float* xT     = ws;             // 524288 floats
  float* ctxT   = ws + 524288;    // 262144
  float* y1T    = ws + 786432;    // 524288
  float* gate2T = ws + 1310720;   // 524288
  float* slotA  = ws + 1835008;   // 524288: gate1T (stages 2-3), then y2T (stages 5-6)
  float* h2     = ws + 2359296;   // 524288 (row-major)
  float* gate1T = slotA;
  float* y2T    = slotA;

  transpose2_k<<<768, 256, 0, stream>>>(x, xT, ctx, ctxT);
  dend_gates_kernel<<<2 * HID / 2, 256, 0, stream>>>(segW1, maskS1, segW2, maskS2,
                                                     ctxT, gate1T, gate2T);
  ff_kernel<<<HID / 4, 256, 0, stream>>>(W1, maskW1, b1, xT, gate1T, y1T);
  topk_kernel<<<B_SZ, 64, 0, stream>>>(y1T, y1T, 0);    // h1T in place
  ff_kernel<<<HID / 4, 256, 0, stream>>>(W2, maskW2, b2, y1T, gate2T, y2T);
  topk_kernel<<<B_SZ, 64, 0, stream>>>(y2T, h2, 1);     // h2 rows
  out_kernel<<<B_SZ, 256, 0, stream>>>(h2, Wex, Wix, Wei, bo, out);
}

// Round 3
// 488.810 us; speedup vs baseline: 1.1187x; 1.1187x over previous
//
#include <hip/hip_runtime.h>
#include <math.h>

#define B_SZ   256
#define D_IN   2048
#define HID    2048
#define NSEG   10
#define D_CTX  1024
#define OUT_N  100
#define KWIN   102
#define CAPS   128   // per-1024-chunk compaction cap (mean 51.2, +11 sigma safe)

typedef float f32x4 __attribute__((ext_vector_type(4)));

// non-temporal 16B load: weight/mask streams must not evict L2-resident activations
__device__ __forceinline__ f32x4 ntld4(const float* p) {
  return __builtin_nontemporal_load((const f32x4*)p);
}

// ---------- sortable-key helpers for exact fp32 top-k ----------
__device__ __forceinline__ unsigned f2key(float f) {
  unsigned b = __float_as_uint(f);
  return (b & 0x80000000u) ? ~b : (b | 0x80000000u);
}
__device__ __forceinline__ float key2f(unsigned k) {
  return (k & 0x80000000u) ? __uint_as_float(k & 0x7FFFFFFFu) : __uint_as_float(~k);
}

// ---------- combined transpose for x and ctx (one launch) ----------
__global__ __launch_bounds__(256) void transpose2_k(const float* __restrict__ xsrc,
                                                    float* __restrict__ xdst,
                                                    const float* __restrict__ csrc,
                                                    float* __restrict__ cdst) {
  __shared__ float tile[32][33];
  int bid = blockIdx.x;
  const float* src; float* dst; int cols;
  const int NX = (D_IN / 32) * (B_SZ / 32);  // 512
  if (bid < NX) { src = xsrc; dst = xdst; cols = D_IN; }
  else { bid -= NX; src = csrc; dst = cdst; cols = D_CTX; }
  int nbx = cols / 32;
  int bx = bid % nbx, by = bid / nbx;
  int c0 = bx * 32, r0 = by * 32;
  int tx = threadIdx.x & 31, ty = threadIdx.x >> 5;
  for (int i = ty; i < 32; i += 8)
    tile[i][tx] = src[(r0 + i) * cols + (c0 + tx)];
  __syncthreads();
  for (int i = ty; i < 32; i += 8)
    dst[(c0 + i) * B_SZ + (r0 + tx)] = tile[tx][i];
}

// ---------- ballot-compact a 1024-float (w,mask) chunk into (w, idx+coff) pairs ----------
// No reg-prefetch (keeps live set < 64 VGPR => no spill); 8 streaming loads in flight.
__device__ __forceinline__ int compact_pairs_1024(const float* __restrict__ wrow,
                                                  const float* __restrict__ mrow,
                                                  int coff, float2* pairs) {
  const int t = threadIdx.x & 63;
  const unsigned long long below = (1ull << t) - 1ull;
  __builtin_amdgcn_wave_barrier();   // don't migrate LDS writes above prior pair reads
  int base = 0;
#pragma unroll
  for (int i = 0; i < 4; ++i) {
    const int e = t + 64 * i;
    f32x4 ww = ntld4(wrow + 4 * e);
    f32x4 mm = ntld4(mrow + 4 * e);
    const float wv[4] = {ww.x, ww.y, ww.z, ww.w};
    const float mv[4] = {mm.x, mm.y, mm.z, mm.w};
    const int c = (e << 2) + coff;
#pragma unroll
    for (int j = 0; j < 4; ++j) {
      bool nz = (mv[j] != 0.f);
      unsigned long long bal = __ballot(nz);
      if (nz) {
        int pos = base + (int)__popcll(bal & below);
        if (pos < CAPS) pairs[pos] = make_float2(wv[j], __int_as_float(c + j));
      }
      base += (int)__popcll(bal);
    }
  }
  __builtin_amdgcn_wave_barrier();
  return base > CAPS ? CAPS : base;
}

// ---------- sparse dot, unroll-8 (8 outstanding 1KB loads/wave) ----------
__device__ __forceinline__ void gather_dot(const float* __restrict__ src,
                                           const float2* pairs, int cnt,
                                           int t4, float out4[4]) {
  float acc[4][4];
#pragma unroll
  for (int s = 0; s < 4; ++s)
#pragma unroll
    for (int i = 0; i < 4; ++i) acc[s][i] = 0.f;
  int j = 0;
  for (; j + 8 <= cnt; j += 8) {
#pragma unroll
    for (int s = 0; s < 8; ++s) {
      float2 p = pairs[j + s];
      const f32x4 cv = *(const f32x4*)(src + (__float_as_int(p.y) << 8) + t4);
      acc[s & 3][0] += cv.x * p.x; acc[s & 3][1] += cv.y * p.x;
      acc[s & 3][2] += cv.z * p.x; acc[s & 3][3] += cv.w * p.x;
    }
  }
  for (; j < cnt; ++j) {
    float2 p = pairs[j];
    const f32x4 cv = *(const f32x4*)(src + (__float_as_int(p.y) << 8) + t4);
    acc[0][0] += cv.x * p.x; acc[0][1] += cv.y * p.x;
    acc[0][2] += cv.z * p.x; acc[0][3] += cv.w * p.x;
  }
#pragma unroll
  for (int i = 0; i < 4; ++i)
    out4[i] = (acc[0][i] + acc[1][i]) + (acc[2][i] + acc[3][i]);
}

// ---------- fused dendrites + FF1: 2048 blocks, 2 units/block, 2 waves/unit ----------
// Wave (pidx,half): 5 segs (half*5..) + [L1 only] half of the FF1 row (~51 nnz = 1 seg-equiv).
// Balanced: L1 wave = 6 chunks, L2 wave = 5. y1 written directly (no gate1T materialized).
__global__ __launch_bounds__(256, 4) void dendff_kernel(
    const float* __restrict__ W1, const float* __restrict__ maskW1, const float* __restrict__ b1,
    const float* __restrict__ segW1, const float* __restrict__ maskS1,
    const float* __restrict__ segW2, const float* __restrict__ maskS2,
    const float* __restrict__ xT, const float* __restrict__ ctxT,
    float* __restrict__ y1T, float* __restrict__ gate2T) {
  __shared__ float2 pairs_s[4][CAPS];
  __shared__ float exch[2][64][13];   // bestA[4], chosen[4], ff[4]; stride 13 (odd) = conflict-light
  const int wave = threadIdx.x >> 6;
  const int t = threadIdx.x & 63, t4 = t * 4;
  const int pidx = wave >> 1;        // unit-in-block
  const int half = wave & 1;         // 0 -> segs 0..4 + FF[0,1024); 1 -> segs 5..9 + FF[1024,2048)
  const int row = blockIdx.x * 2 + pidx;       // 0..4095
  const bool isL1 = (row < HID);
  const int u = isL1 ? row : (row - HID);
  const float* segW = (isL1 ? segW1 : segW2)
                      + (size_t)u * NSEG * D_CTX + (size_t)half * 5 * D_CTX;
  const float* maskS = (isL1 ? maskS1 : maskS2)
                      + (size_t)u * NSEG * D_CTX + (size_t)half * 5 * D_CTX;
  float2* pairs = pairs_s[wave];

  float bestA[4] = {-1.f, -1.f, -1.f, -1.f};
  float chosen[4] = {0.f, 0.f, 0.f, 0.f};

#pragma unroll 1
  for (int s = 0; s < 5; ++s) {
    int cnt = compact_pairs_1024(segW + s * D_CTX, maskS + s * D_CTX, 0, pairs);
    float d[4];
    gather_dot(ctxT, pairs, cnt, t4, d);
#pragma unroll
    for (int i = 0; i < 4; ++i) {
      float a = fabsf(d[i]);
      if (a > bestA[i]) { bestA[i] = a; chosen[i] = d[i]; }  // strict > == first occurrence
    }
  }

  float ffp[4] = {0.f, 0.f, 0.f, 0.f};
  if (isL1) {   // wave-uniform branch (blockIdx-derived): ballots inside remain legal
    const int off = half * 1024;
    int cnt = compact_pairs_1024(W1 + (size_t)u * D_IN + off,
                                 maskW1 + (size_t)u * D_IN + off, off, pairs);
    gather_dot(xT, pairs, cnt, t4, ffp);
  }

  if (half) {
#pragma unroll
    for (int i = 0; i < 4; ++i) {
      exch[pidx][t][i] = bestA[i];
      exch[pidx][t][4 + i] = chosen[i];
      exch[pidx][t][8 + i] = ffp[i];
    }
  }
  __syncthreads();
  if (!half) {
#pragma unroll
    for (int i = 0; i < 4; ++i) {
      float a1 = exch[pidx][t][i];
      if (a1 > bestA[i]) chosen[i] = exch[pidx][t][4 + i];  // half-0 wins ties (lower seg)
      ffp[i] += exch[pidx][t][8 + i];
    }
    if (isL1) {
      float bb = b1[u];
      float4 o;
      o.x = (ffp[0] + bb) / (1.f + expf(-chosen[0]));
      o.y = (ffp[1] + bb) / (1.f + expf(-chosen[1]));
      o.z = (ffp[2] + bb) / (1.f + expf(-chosen[2]));
      o.w = (ffp[3] + bb) / (1.f + expf(-chosen[3]));
      *(float4*)(y1T + (size_t)u * B_SZ + t4) = o;
    } else {
      float4 g;
      g.x = 1.f / (1.f + expf(-chosen[0]));
      g.y = 1.f / (1.f + expf(-chosen[1]));
      g.z = 1.f / (1.f + expf(-chosen[2]));
      g.w = 1.f / (1.f + expf(-chosen[3]));
      *(float4*)(gate2T + (size_t)u * B_SZ + t4) = g;
    }
  }
}

// ---------- FF2: 1024 blocks, 2 units/block, 2 waves/unit (half-row each) ----------
__global__ __launch_bounds__(256, 4) void ff2_kernel(
    const float* __restrict__ W2, const float* __restrict__ maskW2, const float* __restrict__ b2,
    const float* __restrict__ h1T, const float* __restrict__ gate2T, float* __restrict__ y2T) {
  __shared__ float2 pairs_s[4][CAPS];
  __shared__ float exch[2][64][5];
  const int wave = threadIdx.x >> 6;
  const int t = threadIdx.x & 63, t4 = t * 4;
  const int pidx = wave >> 1, half = wave & 1;
  const int u = blockIdx.x * 2 + pidx;
  const int off = half * 1024;
  int cnt = compact_pairs_1024(W2 + (size_t)u * HID + off,
                               maskW2 + (size_t)u * HID + off, off, pairs_s[wave]);
  float acc[4];
  gather_dot(h1T, pairs_s[wave], cnt, t4, acc);
  if (half) {
#pragma unroll
    for (int i = 0; i < 4; ++i) exch[pidx][t][i] = acc[i];
  }
  __syncthreads();
  if (!half) {
#pragma unroll
    for (int i = 0; i < 4; ++i) acc[i] += exch[pidx][t][i];
    float bb = b2[u];
    float4 g = *(const float4*)(gate2T + (size_t)u * B_SZ + t4);
    float4 o;
    o.x = (acc[0] + bb) * g.x; o.y = (acc[1] + bb) * g.y;
    o.z = (acc[2] + bb) * g.z; o.w = (acc[3] + bb) * g.w;
    *(float4*)(y2T + (size_t)u * B_SZ + t4) = o;
  }
}

// ---------- exact top-K per batch column of yT [HID][B]; radix select, stable ties ----------
// (proven r0 version) mode 0: write in place ([HID][B] layout)
__global__ __launch_bounds__(256) void topk_kernel(const float* __restrict__ yT,
                                                   float* __restrict__ dst, int mode) {
  const int b = blockIdx.x, t = threadIdx.x;
  __shared__ int hist[256];
  __shared__ int sfx[256];
  __shared__ unsigned sPref;
  __shared__ int sRem;
  unsigned myk[8];
#pragma unroll
  for (int i = 0; i < 8; ++i)
    myk[i] = f2key(yT[(size_t)(t * 8 + i) * B_SZ + b]);
  unsigned pref = 0;
  int rem = KWIN;
  for (int shift = 24; shift >= 0; shift -= 8) {
    hist[t] = 0;
    __syncthreads();
    unsigned hiMask = (shift == 24) ? 0u : (0xFFFFFFFFu << (shift + 8));
#pragma unroll
    for (int i = 0; i < 8; ++i) {
      unsigned k = myk[i];
      if ((k & hiMask) == pref) atomicAdd(&hist[(k >> shift) & 255], 1);
    }
    __syncthreads();
    sfx[t] = hist[t];
    __syncthreads();
    for (int off = 1; off < 256; off <<= 1) {
      int add = (t + off < 256) ? sfx[t + off] : 0;
      __syncthreads();
      sfx[t] += add;
      __syncthreads();
    }
    int s_incl = sfx[t];
    int s_excl = (t == 255) ? 0 : sfx[t + 1];
    if (s_incl >= rem && s_excl < rem) {
      sPref = pref | (((unsigned)t) << shift);
      sRem = rem - s_excl;
    }
    __syncthreads();
    pref = sPref;
    rem = sRem;
    __syncthreads();
  }
  int eq = 0;
#pragma unroll
  for (int i = 0; i < 8; ++i) eq += (myk[i] == pref) ? 1 : 0;
  sfx[t] = eq;
  __syncthreads();
  for (int off = 1; off < 256; off <<= 1) {
    int add = (t >= off) ? sfx[t - off] : 0;
    __syncthreads();
    sfx[t] += add;
    __syncthreads();
  }
  int excl = sfx[t] - eq;
  int taken = 0;
#pragma unroll
  for (int i = 0; i < 8; ++i) {
    unsigned k = myk[i];
    bool keep;
    if (k > pref) keep = true;
    else if (k == pref) { keep = (excl + taken) < rem; taken++; }
    else keep = false;
    float f = keep ? key2f(k) : 0.f;
    int uu = t * 8 + i;
    if (mode == 0) dst[(size_t)uu * B_SZ + b] = f;
    else dst[(size_t)b * HID + uu] = f;
  }
}

// ---------- fused topk2 + Dale output head: radix-select into LDS, then head ----------
__global__ __launch_bounds__(256) void topkout_kernel(
    const float* __restrict__ yT, const float* __restrict__ Wex, const float* __restrict__ Wix,
    const float* __restrict__ Wei, const float* __restrict__ bo, float* __restrict__ out) {
  const int b = blockIdx.x, t = threadIdx.x;
  __shared__ int hist[256];
  __shared__ int sfx[256];
  __shared__ unsigned sPref;
  __shared__ int sRem;
  __shared__ float hrow[HID];
  __shared__ float red[256];
  unsigned myk[8];
#pragma unroll
  for (int i = 0; i < 8; ++i)
    myk[i] = f2key(yT[(size_t)(t * 8 + i) * B_SZ + b]);
  unsigned pref = 0;
  int rem = KWIN;
  for (int shift = 24; shift >= 0; shift -= 8) {
    hist[t] = 0;
    __syncthreads();
    unsigned hiMask = (shift == 24) ? 0u : (0xFFFFFFFFu << (shift + 8));
#pragma unroll
    for (int i = 0; i < 8; ++i) {
      unsigned k = myk[i];
      if ((k & hiMask) == pref) atomicAdd(&hist[(k >> shift) & 255], 1);
    }
    __syncthreads();
    sfx[t] = hist[t];
    __syncthreads();
    for (int off = 1; off < 256; off <<= 1) {
      int add = (t + off < 256) ? sfx[t + off] : 0;
      __syncthreads();
      sfx[t] += add;
      __syncthreads();
    }
    int s_incl = sfx[t];
    int s_excl = (t == 255) ? 0 : sfx[t + 1];
    if (s_incl >= rem && s_excl < rem) {
      sPref = pref | (((unsigned)t) << shift);
      sRem = rem - s_excl;
    }
    __syncthreads();
    pref = sPref;
    rem = sRem;
    __syncthreads();
  }
  int eq = 0;
#pragma unroll
  for (int i = 0; i < 8; ++i) eq += (myk[i] == pref) ? 1 : 0;
  sfx[t] = eq;
  __syncthreads();
  for (int off = 1; off < 256; off <<= 1) {
    int add = (t >= off) ? sfx[t - off] : 0;
    __syncthreads();
    sfx[t] += add;
    __syncthreads();
  }
  int excl = sfx[t] - eq;
  int taken = 0;
  float part = 0.f;
#pragma unroll
  for (int i = 0; i < 8; ++i) {
    unsigned k = myk[i];
    bool keep;
    if (k > pref) keep = true;
    else if (k == pref) { keep = (excl + taken) < rem; taken++; }
    else keep = false;
    float f = keep ? key2f(k) : 0.f;
    int uu = t * 8 + i;
    hrow[uu] = f;
    part += f * Wix[uu];
  }
  red[t] = part;
  __syncthreads();   // also publishes hrow
  for (int off = 128; off > 0; off >>= 1) {
    if (t < off) red[t] += red[t + off];
    __syncthreads();
  }
  float S = red[0];
  const int w = t >> 6, l = t & 63;
  for (int o = w; o < OUT_N; o += 4) {
    float acc = 0.f;
    const float* wr = Wex + (size_t)o * HID;
#pragma unroll
    for (int q = 0; q < HID / 64; ++q) acc += hrow[l + 64 * q] * wr[l + 64 * q];
    for (int off = 32; off > 0; off >>= 1) acc += __shfl_down(acc, off, 64);
    if (l == 0) out[(size_t)b * OUT_N + o] = acc - Wei[o] * S + bo[o];
  }
}

extern "C" void kernel_launch(void* const* d_in, const int* in_sizes, int n_in,
                              void* d_out, int out_size, void* d_ws, size_t ws_size,
                              hipStream_t stream) {
  const float* x      = (const float*)d_in[0];
  const float* ctx    = (const float*)d_in[1];
  const float* W1     = (const float*)d_in[2];
  const float* b1     = (const float*)d_in[3];
  const float* segW1  = (const float*)d_in[4];
  const float* maskW1 = (const float*)d_in[5];
  const float* maskS1 = (const float*)d_in[6];
  const float* W2     = (const float*)d_in[7];
  const float* b2     = (const float*)d_in[8];
  const float* segW2  = (const float*)d_in[9];
  const float* maskW2 = (const float*)d_in[10];
  const float* maskS2 = (const float*)d_in[11];
  const float* Wex    = (const float*)d_in[12];
  const float* Wix    = (const float*)d_in[13];
  const float* Wei    = (const float*)d_in[14];
  const float* bo     = (const float*)d_in[15];
  float* out = (float*)d_out;
  float* ws = (float*)d_ws;

  float* xT     = ws;             // 524288 floats
  float* ctxT   = ws + 524288;    // 262144
  float* y1T    = ws + 786432;    // 524288 (becomes h1T in place)
  float* gate2T = ws + 1310720;   // 524288
  float* y2T    = ws + 1835008;   // 524288  — total ~9.4 MB

  transpose2_k<<<768, 256, 0, stream>>>(x, xT, ctx, ctxT);
  dendff_kernel<<<2 * HID / 2, 256, 0, stream>>>(W1, maskW1, b1, segW1, maskS1,
                                                 segW2, maskS2, xT, ctxT, y1T, gate2T);
  topk_kernel<<<B_SZ, 256, 0, stream>>>(y1T, y1T, 0);   // h1T in place
  ff2_kernel<<<HID / 2, 256, 0, stream>>>(W2, maskW2, b2, y1T, gate2T, y2T);
  topkout_kernel<<<B_SZ, 256, 0, stream>>>(y2T, Wex, Wix, Wei, bo, out);
}